// Round 14
// baseline (148.066 us; speedup 1.0000x reference)
//
#include <hip/hip_runtime.h>
#include <hip/hip_bf16.h>

// Problem constants
#define B_ 2
#define S_ 2048
#define H_ 8
#define HD_ 64
#define WIN_ 64
#define SUB_ 129      // 1 + 2*WIN
#define D_ 512        // H*HD
#define KS_ 2048
#define M_ 4096       // B*S
#define LN_EPS 1e-3f

typedef unsigned short u16;
typedef short bf16x8 __attribute__((ext_vector_type(8)));
typedef float f32x4 __attribute__((ext_vector_type(4)));

// RNE float->bf16 (finite inputs only)
__device__ inline u16 f2bf(float x) {
  unsigned int u = __float_as_uint(x);
  return (u16)((u + 0x7fffu + ((u >> 16) & 1u)) >> 16);
}
__device__ inline float bf2f(u16 u) {
  return __uint_as_float(((unsigned int)u) << 16);
}
__device__ inline float bf2f_lo(unsigned int u) { return __uint_as_float(u << 16); }
__device__ inline float bf2f_hi(unsigned int u) { return __uint_as_float(u & 0xffff0000u); }

__device__ inline void gll16(const u16* g, u16* l) {
  __builtin_amdgcn_global_load_lds(
      (const __attribute__((address_space(1))) void*)g,
      (__attribute__((address_space(3))) void*)l, 16, 0, 0);
}

// ---------------------------------------------------------------------------
// gemm2: 128x128 tile, BK=64, dbuf gll16 (short-K GEMMs are staging-traffic
// bound). Swapped-operand MFMA + packed ushort4 epilogue. EPI 1 = relu.
// ---------------------------------------------------------------------------
template <int EPI>
__global__ __launch_bounds__(256) void mfma_gemm(
    const u16* __restrict__ A, const u16* __restrict__ Bt,
    const float* __restrict__ bias, u16* __restrict__ Cout, int K, int lda,
    int ldb, int ldc, int TN) {
  __shared__ __align__(16) u16 As[2][8192];   // 128 x 64
  __shared__ __align__(16) u16 Bs[2][8192];

  const int tid = threadIdx.x;
  const int wv = tid >> 6;
  const int ln = tid & 63;

  const int id = blockIdx.x;
  const int xcd = id & 7;
  const int sub = id >> 3;
  const int tn = sub % TN;
  const int msub = sub / TN;
  const int row0 = (xcd * 4 + msub) << 7;
  const int col0 = tn << 7;

  const int lrow = ln >> 3;
  const int lchunk = (ln & 7) ^ lrow;
  const u16* ag = A + (size_t)(row0 + 32 * wv + lrow) * lda + lchunk * 8;
  const u16* bg = Bt + (size_t)(col0 + 32 * wv + lrow) * ldb + lchunk * 8;
  const int lbase = 32 * wv * 64;

  const int quad = ln >> 4;
  const int l15 = ln & 15;
  const int r7 = l15 & 7;
  const int wm = (wv & 1) << 6;
  const int wn = (wv >> 1) << 6;

  f32x4 acc[4][4];
#pragma unroll
  for (int i = 0; i < 4; ++i)
#pragma unroll
    for (int j = 0; j < 4; ++j) acc[i][j] = (f32x4){0.f, 0.f, 0.f, 0.f};

#define STAGE(buf, koff)                                            \
  do {                                                              \
    const u16* a0 = ag + (koff);                                    \
    const u16* b0 = bg + (koff);                                    \
    u16* la = &As[buf][lbase];                                      \
    u16* lb = &Bs[buf][lbase];                                      \
    gll16(a0, la);                                                  \
    gll16(a0 + 8 * (size_t)lda, la + 512);                          \
    gll16(a0 + 16 * (size_t)lda, la + 1024);                       \
    gll16(a0 + 24 * (size_t)lda, la + 1536);                       \
    gll16(b0, lb);                                                  \
    gll16(b0 + 8 * (size_t)ldb, lb + 512);                          \
    gll16(b0 + 16 * (size_t)ldb, lb + 1024);                       \
    gll16(b0 + 24 * (size_t)ldb, lb + 1536);                       \
  } while (0)

  const int nk = K >> 6;
  STAGE(0, 0);

  for (int ki = 0; ki < nk; ++ki) {
    __syncthreads();
    if (ki + 1 < nk) STAGE((ki + 1) & 1, (ki + 1) << 6);

    const char* Ab = (const char*)As[ki & 1];
    const char* Bb = (const char*)Bs[ki & 1];
#pragma unroll
    for (int ks = 0; ks < 2; ++ks) {
      const int pc = ((quad + 4 * ks) ^ r7) << 4;
      bf16x8 af[4], bfv[4];
#pragma unroll
      for (int mi = 0; mi < 4; ++mi)
        af[mi] = *(const bf16x8*)(Ab + (wm + 16 * mi + l15) * 128 + pc);
#pragma unroll
      for (int ni = 0; ni < 4; ++ni)
        bfv[ni] = *(const bf16x8*)(Bb + (wn + 16 * ni + l15) * 128 + pc);
#pragma unroll
      for (int mi = 0; mi < 4; ++mi)
#pragma unroll
        for (int ni = 0; ni < 4; ++ni)
          acc[mi][ni] = __builtin_amdgcn_mfma_f32_16x16x32_bf16(
              bfv[ni], af[mi], acc[mi][ni], 0, 0, 0);
    }
  }
#undef STAGE

  const int c00 = col0 + wn + (quad << 2);
  float4 bv[4];
#pragma unroll
  for (int ni = 0; ni < 4; ++ni) bv[ni] = *(const float4*)&bias[c00 + ni * 16];

#pragma unroll
  for (int mi = 0; mi < 4; ++mi) {
    const int row = row0 + wm + 16 * mi + l15;
#pragma unroll
    for (int ni = 0; ni < 4; ++ni) {
      float v0 = acc[mi][ni][0] + bv[ni].x;
      float v1 = acc[mi][ni][1] + bv[ni].y;
      float v2 = acc[mi][ni][2] + bv[ni].z;
      float v3 = acc[mi][ni][3] + bv[ni].w;
      if (EPI == 1) {
        v0 = fmaxf(v0, 0.f); v1 = fmaxf(v1, 0.f);
        v2 = fmaxf(v2, 0.f); v3 = fmaxf(v3, 0.f);
      }
      ushort4 o = {f2bf(v0), f2bf(v1), f2bf(v2), f2bf(v3)};
      *(ushort4*)&Cout[(size_t)row * ldc + c00 + ni * 16] = o;
    }
  }
}

// ---------------------------------------------------------------------------
// gemm1: 128x96 tile, grid 512 = 2 blocks/CU balanced, BK=64 dbuf.
// A staged DIRECTLY from fp32 `values` with inline f2bf through VGPRs
// (replicates the gll16 slot layout exactly: row 32wv+8j+lrow, phys chunk
// ln&7 holds source chunk lchunk=(ln&7)^lrow). B staged via gll16.
// Removes the vals_bf intermediate (saves ~34 MB HBM round trip).
// Epilogue: bf16 out + per-row LN-stats atomics per 16-col fragment.
// ---------------------------------------------------------------------------
__global__ __launch_bounds__(256) void mfma_gemm96(
    const float* __restrict__ Af, const u16* __restrict__ Bt,
    const float* __restrict__ bias, u16* __restrict__ Cout,
    float* __restrict__ stats, int K, int lda, int ldb, int ldc) {
  __shared__ __align__(16) u16 As[2][8192];   // 128 x 64
  __shared__ __align__(16) u16 Bs[2][6144];   // 96 x 64

  const int tid = threadIdx.x;
  const int wv = tid >> 6;
  const int ln = tid & 63;

  const int id = blockIdx.x;
  const int xcd = id & 7;
  const int sub = id >> 3;        // 0..63
  const int tn = sub & 15;        // 16 col tiles of 96
  const int msub = sub >> 4;      // 4 M-subtiles
  const int row0 = (xcd * 4 + msub) << 7;
  const int col0 = tn * 96;

  const int lrow = ln >> 3;
  const int lchunk = (ln & 7) ^ lrow;
  const float* ag = Af + (size_t)(row0 + 32 * wv + lrow) * lda + lchunk * 8;
  const u16* bg = Bt + (size_t)(col0 + 24 * wv + lrow) * ldb + lchunk * 8;
  u16* const law = (u16*)0;  // unused sentinel
  const int labase = 2048 * wv + lrow * 64 + (ln & 7) * 8;

  const int quad = ln >> 4;
  const int l15 = ln & 15;
  const int r7 = l15 & 7;
  const int wm = (wv & 1) << 6;
  const int wn = (wv >> 1) * 48;

  f32x4 acc[4][3];
#pragma unroll
  for (int i = 0; i < 4; ++i)
#pragma unroll
    for (int j = 0; j < 3; ++j) acc[i][j] = (f32x4){0.f, 0.f, 0.f, 0.f};

#define STAGE96(buf, koff)                                          \
  do {                                                              \
    const float* a0 = ag + (koff);                                  \
    const u16* b0 = bg + (koff);                                    \
    u16* la = &As[buf][labase];                                     \
    u16* lb = &Bs[buf][1536 * wv];                                  \
    _Pragma("unroll")                                               \
    for (int j = 0; j < 4; ++j) {                                   \
      float4 x = *(const float4*)(a0 + (size_t)(8 * j) * lda);      \
      float4 y = *(const float4*)(a0 + (size_t)(8 * j) * lda + 4);  \
      union { u16 u[8]; uint4 v; } pk;                              \
      pk.u[0] = f2bf(x.x); pk.u[1] = f2bf(x.y);                     \
      pk.u[2] = f2bf(x.z); pk.u[3] = f2bf(x.w);                     \
      pk.u[4] = f2bf(y.x); pk.u[5] = f2bf(y.y);                     \
      pk.u[6] = f2bf(y.z); pk.u[7] = f2bf(y.w);                     \
      *(uint4*)(la + j * 512) = pk.v;                               \
    }                                                               \
    gll16(b0, lb);                                                  \
    gll16(b0 + 8 * (size_t)ldb, lb + 512);                          \
    gll16(b0 + 16 * (size_t)ldb, lb + 1024);                       \
  } while (0)

  const int nk = K >> 6;
  STAGE96(0, 0);

  for (int ki = 0; ki < nk; ++ki) {
    __syncthreads();
    if (ki + 1 < nk) STAGE96((ki + 1) & 1, (ki + 1) << 6);

    const char* Ab = (const char*)As[ki & 1];
    const char* Bb = (const char*)Bs[ki & 1];
#pragma unroll
    for (int ks = 0; ks < 2; ++ks) {
      const int pc = ((quad + 4 * ks) ^ r7) << 4;
      bf16x8 af[4], bfv[3];
#pragma unroll
      for (int mi = 0; mi < 4; ++mi)
        af[mi] = *(const bf16x8*)(Ab + (wm + 16 * mi + l15) * 128 + pc);
#pragma unroll
      for (int ni = 0; ni < 3; ++ni)
        bfv[ni] = *(const bf16x8*)(Bb + (wn + 16 * ni + l15) * 128 + pc);
#pragma unroll
      for (int mi = 0; mi < 4; ++mi)
#pragma unroll
        for (int ni = 0; ni < 3; ++ni)
          acc[mi][ni] = __builtin_amdgcn_mfma_f32_16x16x32_bf16(
              bfv[ni], af[mi], acc[mi][ni], 0, 0, 0);
    }
  }
#undef STAGE96
  (void)law;

  const int c00 = col0 + wn + (quad << 2);
  float4 bv[3];
  int half[3];
  bool hk = false, hq = false;
#pragma unroll
  for (int ni = 0; ni < 3; ++ni) {
    bv[ni] = *(const float4*)&bias[c00 + ni * 16];
    const int cb = col0 + wn + ni * 16;   // 16-aligned fragment base
    half[ni] = cb >> 9;                   // 0=k, 1=q, >=2=v
    if (half[ni] == 0) hk = true;
    if (half[ni] == 1) hq = true;
  }

#pragma unroll
  for (int mi = 0; mi < 4; ++mi) {
    const int row = row0 + wm + 16 * mi + l15;
    float sk = 0.f, ssk = 0.f, sq = 0.f, ssq = 0.f;
#pragma unroll
    for (int ni = 0; ni < 3; ++ni) {
      float v0 = acc[mi][ni][0] + bv[ni].x;
      float v1 = acc[mi][ni][1] + bv[ni].y;
      float v2 = acc[mi][ni][2] + bv[ni].z;
      float v3 = acc[mi][ni][3] + bv[ni].w;
      if (half[ni] == 0) {
        sk += v0 + v1 + v2 + v3;
        ssk += v0 * v0 + v1 * v1 + v2 * v2 + v3 * v3;
      } else if (half[ni] == 1) {
        sq += v0 + v1 + v2 + v3;
        ssq += v0 * v0 + v1 * v1 + v2 * v2 + v3 * v3;
      }
      ushort4 o = {f2bf(v0), f2bf(v1), f2bf(v2), f2bf(v3)};
      *(ushort4*)&Cout[(size_t)row * ldc + c00 + ni * 16] = o;
    }
    if (hk) {
      sk += __shfl_xor(sk, 16); ssk += __shfl_xor(ssk, 16);
      sk += __shfl_xor(sk, 32); ssk += __shfl_xor(ssk, 32);
      if (quad == 0) {
        atomicAdd(&stats[(size_t)row * 4 + 0], sk);
        atomicAdd(&stats[(size_t)row * 4 + 1], ssk);
      }
    }
    if (hq) {
      sq += __shfl_xor(sq, 16); ssq += __shfl_xor(ssq, 16);
      sq += __shfl_xor(sq, 32); ssq += __shfl_xor(ssq, 32);
      if (quad == 0) {
        atomicAdd(&stats[(size_t)row * 4 + 2], sq);
        atomicAdd(&stats[(size_t)row * 4 + 3], ssq);
      }
    }
  }
}

// ---------------------------------------------------------------------------
// gemm3: 64x64-tile, BK=128 stacked-half staging (r13 win). Grid 512 =
// 2 blocks/CU. fp32 out + bias + bf16 v-residual epilogue.
// ---------------------------------------------------------------------------
__global__ __launch_bounds__(256) void mfma_gemm64(
    const u16* __restrict__ A, const u16* __restrict__ Bt,
    const float* __restrict__ bias, const u16* __restrict__ extra,
    float* __restrict__ Cout, int K, int lda, int ldb, int ldc, int eld) {
  __shared__ __align__(16) u16 As[2][8192];   // [buf][half 4096 | 64r x 64]
  __shared__ __align__(16) u16 Bs[2][8192];

  const int tid = threadIdx.x;
  const int wv = tid >> 6;
  const int ln = tid & 63;

  const int id = blockIdx.x;
  const int xcd = id & 7;
  const int sub = id >> 3;
  const int tn = sub & 7;
  const int msub = sub >> 3;
  const int row0 = (xcd * 8 + msub) << 6;
  const int col0 = tn << 6;

  const int lrow = ln >> 3;
  const int lchunk = (ln & 7) ^ lrow;
  const u16* ag = A + (size_t)(row0 + 16 * wv + lrow) * lda + lchunk * 8;
  const u16* bg = Bt + (size_t)(col0 + 16 * wv + lrow) * ldb + lchunk * 8;
  const int lbase = 16 * wv * 64;   // within a half

  const int quad = ln >> 4;
  const int l15 = ln & 15;
  const int r7 = l15 & 7;
  const int wm = (wv & 1) << 5;
  const int wn = (wv >> 1) << 5;

  f32x4 acc[2][2];
#pragma unroll
  for (int i = 0; i < 2; ++i)
#pragma unroll
    for (int j = 0; j < 2; ++j) acc[i][j] = (f32x4){0.f, 0.f, 0.f, 0.f};

#define STAGE128(buf, koff)                                         \
  do {                                                              \
    const u16* a0 = ag + (koff);                                    \
    const u16* b0 = bg + (koff);                                    \
    u16* la = &As[buf][lbase];                                      \
    u16* lb = &Bs[buf][lbase];                                      \
    gll16(a0, la);                                                  \
    gll16(a0 + 8 * (size_t)lda, la + 512);                          \
    gll16(b0, lb);                                                  \
    gll16(b0 + 8 * (size_t)ldb, lb + 512);                          \
    gll16(a0 + 64, la + 4096);                                      \
    gll16(a0 + 64 + 8 * (size_t)lda, la + 4096 + 512);              \
    gll16(b0 + 64, lb + 4096);                                      \
    gll16(b0 + 64 + 8 * (size_t)ldb, lb + 4096 + 512);              \
  } while (0)

  const int nk = K >> 7;    // 16 iterations at K=2048
  STAGE128(0, 0);

  for (int ki = 0; ki < nk; ++ki) {
    __syncthreads();
    if (ki + 1 < nk) STAGE128((ki + 1) & 1, (ki + 1) << 7);

    const char* Ab = (const char*)As[ki & 1];
    const char* Bb = (const char*)Bs[ki & 1];
#pragma unroll
    for (int ks = 0; ks < 4; ++ks) {
      const int hoff = (ks >> 1) * 8192;   // byte offset of half
      const int pc = ((quad + 4 * (ks & 1)) ^ r7) << 4;
      bf16x8 af[2], bfv[2];
#pragma unroll
      for (int mi = 0; mi < 2; ++mi)
        af[mi] = *(const bf16x8*)(Ab + hoff + (wm + 16 * mi + l15) * 128 + pc);
#pragma unroll
      for (int ni = 0; ni < 2; ++ni)
        bfv[ni] = *(const bf16x8*)(Bb + hoff + (wn + 16 * ni + l15) * 128 + pc);
#pragma unroll
      for (int mi = 0; mi < 2; ++mi)
#pragma unroll
        for (int ni = 0; ni < 2; ++ni)
          acc[mi][ni] = __builtin_amdgcn_mfma_f32_16x16x32_bf16(
              bfv[ni], af[mi], acc[mi][ni], 0, 0, 0);
    }
  }
#undef STAGE128

  const int c00 = col0 + wn + (quad << 2);
  float4 bv[2];
#pragma unroll
  for (int ni = 0; ni < 2; ++ni) bv[ni] = *(const float4*)&bias[c00 + ni * 16];

#pragma unroll
  for (int mi = 0; mi < 2; ++mi) {
    const int row = row0 + wm + 16 * mi + l15;
#pragma unroll
    for (int ni = 0; ni < 2; ++ni) {
      const int c = c00 + ni * 16;
      uint2 ex = *(const uint2*)&extra[(size_t)row * eld + c];
      float4 o;
      o.x = acc[mi][ni][0] + bv[ni].x + bf2f_lo(ex.x);
      o.y = acc[mi][ni][1] + bv[ni].y + bf2f_hi(ex.x);
      o.z = acc[mi][ni][2] + bv[ni].z + bf2f_lo(ex.y);
      o.w = acc[mi][ni][3] + bv[ni].w + bf2f_hi(ex.y);
      *(float4*)&Cout[(size_t)row * ldc + c] = o;
    }
  }
}

// ---------------------------------------------------------------------------
// Fused weight transposes + stats zero-init (one launch, 2833 blocks):
// 0..767 W_kqv^T; 768..1791 W_kernel^T; 1792..2815 W_proj^T;
// 2816..2832 zero LN-stats (17408 floats).
// (values fp32->bf16 convert eliminated: gemm1 stages fp32 directly)
// ---------------------------------------------------------------------------
__global__ __launch_bounds__(256) void fused_cvt(
    const float* __restrict__ Wkqv, u16* __restrict__ wkqv_t,
    const float* __restrict__ Wker, u16* __restrict__ wker_t,
    const float* __restrict__ Wproj, u16* __restrict__ wproj_t,
    float* __restrict__ stats) {
  __shared__ float t[32][33];
  const int id = blockIdx.x;
  if (id >= 2816) {
    const int i = ((id - 2816) * 256 + threadIdx.x) * 4;
    *(float4*)&stats[i] = (float4){0.f, 0.f, 0.f, 0.f};
    return;
  }
  const float* W; u16* Wt; int K, N, nx, lin;
  if (id < 768)       { lin = id;        W = Wkqv;  Wt = wkqv_t;  K = 512;  N = 1536; nx = 48; }
  else if (id < 1792) { lin = id - 768;  W = Wker;  Wt = wker_t;  K = 512;  N = 2048; nx = 64; }
  else                { lin = id - 1792; W = Wproj; Wt = wproj_t; K = 2048; N = 512;  nx = 16; }
  const int n0 = (lin % nx) << 5;
  const int k0 = (lin / nx) << 5;
  const int r = threadIdx.x >> 3;
  const int c4 = (threadIdx.x & 7) << 2;
  float4 v = *(const float4*)&W[(size_t)(k0 + r) * N + n0 + c4];
  t[r][c4 + 0] = v.x; t[r][c4 + 1] = v.y; t[r][c4 + 2] = v.z; t[r][c4 + 3] = v.w;
  __syncthreads();
  ushort4 o;
  o.x = f2bf(t[c4 + 0][r]); o.y = f2bf(t[c4 + 1][r]);
  o.z = f2bf(t[c4 + 2][r]); o.w = f2bf(t[c4 + 3][r]);
  *(ushort4*)&Wt[(size_t)(n0 + r) * K + k0 + c4] = o;
}

// ---------------------------------------------------------------------------
// MFMA windowed attention with fused LayerNorm (stats from gemm1 atomics).
// ---------------------------------------------------------------------------
__global__ __launch_bounds__(256) void attn_kernel(
    const u16* __restrict__ kqv, const float* __restrict__ stats,
    const float* __restrict__ gamma, const float* __restrict__ beta,
    u16* __restrict__ ctx) {
  __shared__ __align__(16) u16 Ks[192 * 64];
  __shared__ __align__(16) u16 Vt[64 * 192];
  __shared__ __align__(16) u16 Ps[4 * 16 * 192];
  __shared__ float kr[192], km[192];
  __shared__ float qm[64], qr[64];
  __shared__ float g1[64], b1[64];

  const int bid = blockIdx.x;      // (b*H + h)*32 + tile
  const int tile = bid & 31;
  const int h = (bid >> 5) & 7;
  const int b = bid >> 8;
  const int t0 = tile << 6;

  int g0 = t0 - WIN_;
  if (g0 < 0) g0 = 0;
  if (g0 > S_ - SUB_) g0 = S_ - SUB_;

  const int tid = threadIdx.x;
  const int wv = tid >> 6;
  const int ln = tid & 63;
  const size_t rowb = (size_t)(b * S_);

  // ---- stage K via global_load_lds (pure copy, swizzled) ----
  {
    const int krow = ln >> 3;                 // 0..7
    const int kch = (ln & 7) ^ krow;          // source chunk
#pragma unroll
    for (int it = 0; it < 6; ++it) {
      const int kb = it * 32 + wv * 8;        // wave's 8-key group
      gll16(&kqv[(rowb + g0 + kb + krow) * 1536 + h * 64 + kch * 8],
            &Ks[kb * 64]);
    }
  }
  // ---- phase 0: LN stats -> LDS ----
  if (tid < 192) {
    const size_t rr = rowb + g0 + tid;
    const float s = stats[rr * 4 + 0], ss = stats[rr * 4 + 1];
    const float mu = s * (1.f / 512.f);
    const float var = ss * (1.f / 512.f) - mu * mu;
    const float rs = rsqrtf(var + LN_EPS);
    kr[tid] = rs * 0.125f;
    km[tid] = mu * rs * 0.125f;
  } else {
    const int t = tid - 192;
    const size_t rr = rowb + t0 + t;
    const float s = stats[rr * 4 + 2], ss = stats[rr * 4 + 3];
    const float mu = s * (1.f / 512.f);
    const float var = ss * (1.f / 512.f) - mu * mu;
    qm[t] = mu;
    qr[t] = rsqrtf(var + LN_EPS);
  }
  // ---- stage V^T: uint4 loads, conflict-free u16 scatter stores ----
#pragma unroll
  for (int it = 0; it < 6; ++it) {
    const int item = tid + it * 256;        // 192 keys * 8 d-octets
    const int dg8 = item / 192;
    const int key = item - dg8 * 192;
    union { uint4 v; u16 u[8]; } uu;
    uu.v = *(const uint4*)&kqv[(rowb + g0 + key) * 1536 + 1024 + h * 64 + dg8 * 8];
    const int c = key >> 3;
#pragma unroll
    for (int j = 0; j < 8; ++j) {
      const int d = dg8 * 8 + j;
      const int phys = (c & 24) | ((c ^ d) & 7);
      Vt[d * 192 + phys * 8 + (key & 7)] = uu.u[j];
    }
  }
  __syncthreads();  // K landed (vmcnt drained), stats + V visible

  // ---- stage Q: full LN then x gamma; accumulate g1/b1 ----
#pragma unroll
  for (int it = 0; it < 2; ++it) {
    const int item = tid + it * 256;        // 64 q * 8 chunks
    const int qq = item >> 3, c = item & 7;
    const int phys = c ^ (qq & 7);
    uint4 v = *(const uint4*)&kqv[(rowb + t0 + qq) * 1536 + 512 + h * 64 + c * 8];
    const float mu = qm[qq], rs = qr[qq];
    union { float4 f4[2]; float f[8]; } gl, bl;
    gl.f4[0] = *(const float4*)&gamma[h * 64 + c * 8];
    gl.f4[1] = *(const float4*)&gamma[h * 64 + c * 8 + 4];
    bl.f4[0] = *(const float4*)&beta[h * 64 + c * 8];
    bl.f4[1] = *(const float4*)&beta[h * 64 + c * 8 + 4];
    const float x[8] = {bf2f_lo(v.x), bf2f_hi(v.x), bf2f_lo(v.y), bf2f_hi(v.y),
                        bf2f_lo(v.z), bf2f_hi(v.z), bf2f_lo(v.w), bf2f_hi(v.w)};
    float g1p = 0.f, b1p = 0.f;
    union { u16 u[8]; uint4 v; } pk;
#pragma unroll
    for (int j = 0; j < 8; ++j) {
      const float qp = (x[j] - mu) * rs * gl.f[j] + bl.f[j];  // Q' (ref LN'd q)
      const u16 qg = f2bf(qp * gl.f[j]);                      // QG = Q'*gamma
      pk.u[j] = qg;
      g1p += bf2f(qg);
      b1p += qp * bl.f[j];
    }
    g1p += __shfl_xor(g1p, 1); b1p += __shfl_xor(b1p, 1);
    g1p += __shfl_xor(g1p, 2); b1p += __shfl_xor(b1p, 2);
    g1p += __shfl_xor(g1p, 4); b1p += __shfl_xor(b1p, 4);
    if ((tid & 7) == 0) { g1[qq] = g1p; b1[qq] = b1p * 0.125f; }
    *(uint4*)&Ps[qq * 64 + phys * 8] = pk.v;
  }
  __syncthreads();  // Qs (QG) + g1/b1 visible

  const int quad = ln >> 4;
  const int l15 = ln & 15;
  const int l7 = l15 & 7;
  const int qbase = wv << 4;

  // Q A-fragments (2 k-steps)
  bf16x8 qf[2];
#pragma unroll
  for (int ks = 0; ks < 2; ++ks) {
    const int phys = (ks * 4 + quad) ^ l7;
    qf[ks] = *(const bf16x8*)&Ps[(qbase + l15) * 64 + phys * 8];
  }

  // QK: raw = QG @ k^T
  f32x4 sacc[12];
#pragma unroll
  for (int nt = 0; nt < 12; ++nt) sacc[nt] = (f32x4){0.f, 0.f, 0.f, 0.f};
#pragma unroll
  for (int ks = 0; ks < 2; ++ks) {
    const int phys = (ks * 4 + quad) ^ l7;
#pragma unroll
    for (int nt = 0; nt < 12; ++nt) {
      bf16x8 kf = *(const bf16x8*)&Ks[(nt * 16 + l15) * 64 + phys * 8];
      sacc[nt] = __builtin_amdgcn_mfma_f32_16x16x32_bf16(qf[ks], kf, sacc[nt], 0, 0, 0);
    }
  }

  // per-row window offsets + per-row correction scalars
  int off[4];
  float g1m[4], b1s[4];
#pragma unroll
  for (int r = 0; r < 4; ++r) {
    const int qg = t0 + qbase + quad * 4 + r;
    int st = qg - WIN_;
    if (st < 0) st = 0;
    if (st > S_ - SUB_) st = S_ - SUB_;
    off[r] = st - g0;
    g1m[r] = g1[qbase + quad * 4 + r];
    b1s[r] = b1[qbase + quad * 4 + r];
  }

  // LN-fold correction + mask + row max  (kr/km carry the 1/8 scale)
  float rmax[4] = {-1e30f, -1e30f, -1e30f, -1e30f};
#pragma unroll
  for (int nt = 0; nt < 12; ++nt) {
    const int n = nt * 16 + l15;
    const float rsn = kr[n], mn = km[n];
#pragma unroll
    for (int r = 0; r < 4; ++r) {
      const bool valid = (n >= off[r]) && (n < off[r] + SUB_);
      const float sv = fmaf(rsn, sacc[nt][r], fmaf(-mn, g1m[r], b1s[r]));
      const float v = valid ? sv : -1e30f;
      sacc[nt][r] = v;
      rmax[r] = fmaxf(rmax[r], v);
    }
  }
#pragma unroll
  for (int m = 1; m < 16; m <<= 1)
#pragma unroll
    for (int r = 0; r < 4; ++r) rmax[r] = fmaxf(rmax[r], __shfl_xor(rmax[r], m));

  // exp + row sum
  float rsum[4] = {0.f, 0.f, 0.f, 0.f};
#pragma unroll
  for (int nt = 0; nt < 12; ++nt) {
#pragma unroll
    for (int r = 0; r < 4; ++r) {
      const float e = __expf(sacc[nt][r] - rmax[r]);
      sacc[nt][r] = e;
      rsum[r] += e;
    }
  }
#pragma unroll
  for (int m = 1; m < 16; m <<= 1)
#pragma unroll
    for (int r = 0; r < 4; ++r) rsum[r] += __shfl_xor(rsum[r], m);
  float inv[4];
#pragma unroll
  for (int r = 0; r < 4; ++r) inv[r] = 1.f / rsum[r];

  __syncthreads();  // QK reads done; Qs region dead

  // write P (bf16, unnormalized) to wave's Ps region, swizzled
  u16* psw = &Ps[wv * 16 * 192];
#pragma unroll
  for (int nt = 0; nt < 12; ++nt) {
    const int n = nt * 16 + l15;
    const int c = n >> 3;
#pragma unroll
    for (int r = 0; r < 4; ++r) {
      const int m = quad * 4 + r;
      const int phys = (c & 24) | ((c ^ m) & 7);
      psw[m * 192 + phys * 8 + (n & 7)] = f2bf(sacc[nt][r]);
    }
  }
  __syncthreads();  // Ps visible

  // PV: O[16 x 64] = P @ (V^T)^T
  f32x4 oacc[4];
#pragma unroll
  for (int nt = 0; nt < 4; ++nt) oacc[nt] = (f32x4){0.f, 0.f, 0.f, 0.f};
#pragma unroll
  for (int ks = 0; ks < 6; ++ks) {
    const int c = ks * 4 + quad;
    const int phys = (c & 24) | ((c ^ l7) & 7);
    bf16x8 pf = *(const bf16x8*)&psw[l15 * 192 + phys * 8];
#pragma unroll
    for (int nt = 0; nt < 4; ++nt) {
      bf16x8 vf = *(const bf16x8*)&Vt[(nt * 16 + l15) * 192 + phys * 8];
      oacc[nt] = __builtin_amdgcn_mfma_f32_16x16x32_bf16(pf, vf, oacc[nt], 0, 0, 0);
    }
  }

  // epilogue
#pragma unroll
  for (int nt = 0; nt < 4; ++nt) {
#pragma unroll
    for (int r = 0; r < 4; ++r) {
      const int row = t0 + qbase + quad * 4 + r;
      const int col = h * 64 + nt * 16 + l15;
      ctx[(rowb + row) * D_ + col] = f2bf(oacc[nt][r] * inv[r]);
    }
  }
}

// ---------------------------------------------------------------------------
extern "C" void kernel_launch(void* const* d_in, const int* in_sizes, int n_in,
                              void* d_out, int out_size, void* d_ws,
                              size_t ws_size, hipStream_t stream) {
  (void)in_sizes; (void)n_in; (void)out_size; (void)ws_size;
  const float* values   = (const float*)d_in[0];
  const float* W_kqv    = (const float*)d_in[1];
  const float* b_kqv    = (const float*)d_in[2];
  const float* ln_gamma = (const float*)d_in[3];
  const float* ln_beta  = (const float*)d_in[4];
  const float* W_kernel = (const float*)d_in[5];
  const float* b_kernel = (const float*)d_in[6];
  const float* W_proj   = (const float*)d_in[7];
  const float* b_proj   = (const float*)d_in[8];
  float* out = (float*)d_out;

  // workspace carve (16-B aligned)
  u16* kqv     = (u16*)d_ws;                     // M x 1536
  u16* ctx_bf  = kqv + (size_t)M_ * 1536;        // M x 512
  u16* x_bf    = ctx_bf + (size_t)M_ * 512;      // M x 2048
  u16* wkqv_t  = x_bf + (size_t)M_ * 2048;       // 1536 x 512
  u16* wker_t  = wkqv_t + (size_t)1536 * 512;    // 2048 x 512
  u16* wproj_t = wker_t + (size_t)2048 * 512;    // 512 x 2048
  float* stats = (float*)(wproj_t + (size_t)512 * 2048);  // 17408 fp32

  // weight transposes + stats zero-init (one launch)
  fused_cvt<<<2833, 256, 0, stream>>>(W_kqv, wkqv_t, W_kernel, wker_t,
                                      W_proj, wproj_t, stats);

  // kqv = values @ W_kqv + b_kqv (bf16 out) + LN stats atomics
  // A staged directly from fp32 values (inline convert)
  mfma_gemm96<<<512, 256, 0, stream>>>(
      values, wkqv_t, b_kqv, kqv, stats, 512, 512, 512, 1536);

  // MFMA windowed attention with fused LN -> ctx (bf16)
  attn_kernel<<<B_ * H_ * (S_ / 64), 256, 0, stream>>>(
      kqv, stats, ln_gamma, ln_beta, ctx_bf);

  // x = relu(ctx @ W_kernel + b_kernel)  (bf16 out), 128x128, 512 blocks
  mfma_gemm<1><<<512, 256, 0, stream>>>(
      ctx_bf, wker_t, b_kernel, x_bf, 512, 512, 512, KS_, 16);

  // out = x @ W_proj + b_proj + v  (fp32 out, 64x64 tiles BK=128, 512 blocks)
  mfma_gemm64<<<512, 256, 0, stream>>>(
      x_bf, wproj_t, b_proj, kqv + 1024, out, KS_, KS_, KS_, D_, 1536);
}

// Round 15
// 143.558 us; speedup vs baseline: 1.0314x; 1.0314x over previous
//
#include <hip/hip_runtime.h>
#include <hip/hip_bf16.h>

// Problem constants
#define B_ 2
#define S_ 2048
#define H_ 8
#define HD_ 64
#define WIN_ 64
#define SUB_ 129      // 1 + 2*WIN
#define D_ 512        // H*HD
#define KS_ 2048
#define M_ 4096       // B*S
#define LN_EPS 1e-3f

typedef unsigned short u16;
typedef short bf16x8 __attribute__((ext_vector_type(8)));
typedef float f32x4 __attribute__((ext_vector_type(4)));

// RNE float->bf16 (finite inputs only)
__device__ inline u16 f2bf(float x) {
  unsigned int u = __float_as_uint(x);
  return (u16)((u + 0x7fffu + ((u >> 16) & 1u)) >> 16);
}
__device__ inline float bf2f(u16 u) {
  return __uint_as_float(((unsigned int)u) << 16);
}
__device__ inline float bf2f_lo(unsigned int u) { return __uint_as_float(u << 16); }
__device__ inline float bf2f_hi(unsigned int u) { return __uint_as_float(u & 0xffff0000u); }

__device__ inline void gll16(const u16* g, u16* l) {
  __builtin_amdgcn_global_load_lds(
      (const __attribute__((address_space(1))) void*)g,
      (__attribute__((address_space(3))) void*)l, 16, 0, 0);
}

// ---------------------------------------------------------------------------
// gemm2: 128x128 tile, BK=64, dbuf gll16 (short-K GEMMs are staging-traffic
// bound, big tiles minimize total staged bytes).
// Swapped-operand MFMA + packed ushort4 epilogue. EPI: 1 = relu(acc+bias).
// ---------------------------------------------------------------------------
template <int EPI>
__global__ __launch_bounds__(256) void mfma_gemm(
    const u16* __restrict__ A, const u16* __restrict__ Bt,
    const float* __restrict__ bias, u16* __restrict__ Cout, int K, int lda,
    int ldb, int ldc, int TN) {
  __shared__ __align__(16) u16 As[2][8192];   // 128 x 64
  __shared__ __align__(16) u16 Bs[2][8192];

  const int tid = threadIdx.x;
  const int wv = tid >> 6;
  const int ln = tid & 63;

  const int id = blockIdx.x;
  const int xcd = id & 7;
  const int sub = id >> 3;
  const int tn = sub % TN;
  const int msub = sub / TN;
  const int row0 = (xcd * 4 + msub) << 7;
  const int col0 = tn << 7;

  const int lrow = ln >> 3;
  const int lchunk = (ln & 7) ^ lrow;
  const u16* ag = A + (size_t)(row0 + 32 * wv + lrow) * lda + lchunk * 8;
  const u16* bg = Bt + (size_t)(col0 + 32 * wv + lrow) * ldb + lchunk * 8;
  const int lbase = 32 * wv * 64;

  const int quad = ln >> 4;
  const int l15 = ln & 15;
  const int r7 = l15 & 7;
  const int wm = (wv & 1) << 6;
  const int wn = (wv >> 1) << 6;

  f32x4 acc[4][4];
#pragma unroll
  for (int i = 0; i < 4; ++i)
#pragma unroll
    for (int j = 0; j < 4; ++j) acc[i][j] = (f32x4){0.f, 0.f, 0.f, 0.f};

#define STAGE(buf, koff)                                            \
  do {                                                              \
    const u16* a0 = ag + (koff);                                    \
    const u16* b0 = bg + (koff);                                    \
    u16* la = &As[buf][lbase];                                      \
    u16* lb = &Bs[buf][lbase];                                      \
    gll16(a0, la);                                                  \
    gll16(a0 + 8 * (size_t)lda, la + 512);                          \
    gll16(a0 + 16 * (size_t)lda, la + 1024);                       \
    gll16(a0 + 24 * (size_t)lda, la + 1536);                       \
    gll16(b0, lb);                                                  \
    gll16(b0 + 8 * (size_t)ldb, lb + 512);                          \
    gll16(b0 + 16 * (size_t)ldb, lb + 1024);                       \
    gll16(b0 + 24 * (size_t)ldb, lb + 1536);                       \
  } while (0)

  const int nk = K >> 6;
  STAGE(0, 0);

  for (int ki = 0; ki < nk; ++ki) {
    __syncthreads();
    if (ki + 1 < nk) STAGE((ki + 1) & 1, (ki + 1) << 6);

    const char* Ab = (const char*)As[ki & 1];
    const char* Bb = (const char*)Bs[ki & 1];
#pragma unroll
    for (int ks = 0; ks < 2; ++ks) {
      const int pc = ((quad + 4 * ks) ^ r7) << 4;
      bf16x8 af[4], bfv[4];
#pragma unroll
      for (int mi = 0; mi < 4; ++mi)
        af[mi] = *(const bf16x8*)(Ab + (wm + 16 * mi + l15) * 128 + pc);
#pragma unroll
      for (int ni = 0; ni < 4; ++ni)
        bfv[ni] = *(const bf16x8*)(Bb + (wn + 16 * ni + l15) * 128 + pc);
#pragma unroll
      for (int mi = 0; mi < 4; ++mi)
#pragma unroll
        for (int ni = 0; ni < 4; ++ni)
          acc[mi][ni] = __builtin_amdgcn_mfma_f32_16x16x32_bf16(
              bfv[ni], af[mi], acc[mi][ni], 0, 0, 0);
    }
  }
#undef STAGE

  const int c00 = col0 + wn + (quad << 2);
  float4 bv[4];
#pragma unroll
  for (int ni = 0; ni < 4; ++ni) bv[ni] = *(const float4*)&bias[c00 + ni * 16];

#pragma unroll
  for (int mi = 0; mi < 4; ++mi) {
    const int row = row0 + wm + 16 * mi + l15;
#pragma unroll
    for (int ni = 0; ni < 4; ++ni) {
      float v0 = acc[mi][ni][0] + bv[ni].x;
      float v1 = acc[mi][ni][1] + bv[ni].y;
      float v2 = acc[mi][ni][2] + bv[ni].z;
      float v3 = acc[mi][ni][3] + bv[ni].w;
      if (EPI == 1) {
        v0 = fmaxf(v0, 0.f); v1 = fmaxf(v1, 0.f);
        v2 = fmaxf(v2, 0.f); v3 = fmaxf(v3, 0.f);
      }
      ushort4 o = {f2bf(v0), f2bf(v1), f2bf(v2), f2bf(v3)};
      *(ushort4*)&Cout[(size_t)row * ldc + c00 + ni * 16] = o;
    }
  }
}

// ---------------------------------------------------------------------------
// gemm1: 128x96 tile, grid 512 = 2 blocks/CU balanced, BK=64 dbuf gll16
// (bf16 A from vals_bf: one-shot convert beats inline fp32 staging because
// A is re-read by 16 column tiles — r14 lesson).
// Epilogue: bf16 out + per-row LN-stats atomics per 16-col fragment.
// ---------------------------------------------------------------------------
__global__ __launch_bounds__(256) void mfma_gemm96(
    const u16* __restrict__ A, const u16* __restrict__ Bt,
    const float* __restrict__ bias, u16* __restrict__ Cout,
    float* __restrict__ stats, int K, int lda, int ldb, int ldc) {
  __shared__ __align__(16) u16 As[2][8192];   // 128 x 64
  __shared__ __align__(16) u16 Bs[2][6144];   // 96 x 64

  const int tid = threadIdx.x;
  const int wv = tid >> 6;
  const int ln = tid & 63;

  const int id = blockIdx.x;
  const int xcd = id & 7;
  const int sub = id >> 3;        // 0..63
  const int tn = sub & 15;        // 16 col tiles of 96
  const int msub = sub >> 4;      // 4 M-subtiles
  const int row0 = (xcd * 4 + msub) << 7;
  const int col0 = tn * 96;

  const int lrow = ln >> 3;
  const int lchunk = (ln & 7) ^ lrow;
  const u16* ag = A + (size_t)(row0 + 32 * wv + lrow) * lda + lchunk * 8;
  const u16* bg = Bt + (size_t)(col0 + 24 * wv + lrow) * ldb + lchunk * 8;

  const int quad = ln >> 4;
  const int l15 = ln & 15;
  const int r7 = l15 & 7;
  const int wm = (wv & 1) << 6;
  const int wn = (wv >> 1) * 48;

  f32x4 acc[4][3];
#pragma unroll
  for (int i = 0; i < 4; ++i)
#pragma unroll
    for (int j = 0; j < 3; ++j) acc[i][j] = (f32x4){0.f, 0.f, 0.f, 0.f};

#define STAGE96(buf, koff)                                          \
  do {                                                              \
    const u16* a0 = ag + (koff);                                    \
    const u16* b0 = bg + (koff);                                    \
    u16* la = &As[buf][2048 * wv];                                  \
    u16* lb = &Bs[buf][1536 * wv];                                  \
    gll16(a0, la);                                                  \
    gll16(a0 + 8 * (size_t)lda, la + 512);                          \
    gll16(a0 + 16 * (size_t)lda, la + 1024);                       \
    gll16(a0 + 24 * (size_t)lda, la + 1536);                       \
    gll16(b0, lb);                                                  \
    gll16(b0 + 8 * (size_t)ldb, lb + 512);                          \
    gll16(b0 + 16 * (size_t)ldb, lb + 1024);                       \
  } while (0)

  const int nk = K >> 6;
  STAGE96(0, 0);

  for (int ki = 0; ki < nk; ++ki) {
    __syncthreads();
    if (ki + 1 < nk) STAGE96((ki + 1) & 1, (ki + 1) << 6);

    const char* Ab = (const char*)As[ki & 1];
    const char* Bb = (const char*)Bs[ki & 1];
#pragma unroll
    for (int ks = 0; ks < 2; ++ks) {
      const int pc = ((quad + 4 * ks) ^ r7) << 4;
      bf16x8 af[4], bfv[3];
#pragma unroll
      for (int mi = 0; mi < 4; ++mi)
        af[mi] = *(const bf16x8*)(Ab + (wm + 16 * mi + l15) * 128 + pc);
#pragma unroll
      for (int ni = 0; ni < 3; ++ni)
        bfv[ni] = *(const bf16x8*)(Bb + (wn + 16 * ni + l15) * 128 + pc);
#pragma unroll
      for (int mi = 0; mi < 4; ++mi)
#pragma unroll
        for (int ni = 0; ni < 3; ++ni)
          acc[mi][ni] = __builtin_amdgcn_mfma_f32_16x16x32_bf16(
              bfv[ni], af[mi], acc[mi][ni], 0, 0, 0);
    }
  }
#undef STAGE96

  const int c00 = col0 + wn + (quad << 2);
  float4 bv[3];
  int half[3];
  bool hk = false, hq = false;
#pragma unroll
  for (int ni = 0; ni < 3; ++ni) {
    bv[ni] = *(const float4*)&bias[c00 + ni * 16];
    const int cb = col0 + wn + ni * 16;   // 16-aligned fragment base
    half[ni] = cb >> 9;                   // 0=k, 1=q, >=2=v
    if (half[ni] == 0) hk = true;
    if (half[ni] == 1) hq = true;
  }

#pragma unroll
  for (int mi = 0; mi < 4; ++mi) {
    const int row = row0 + wm + 16 * mi + l15;
    float sk = 0.f, ssk = 0.f, sq = 0.f, ssq = 0.f;
#pragma unroll
    for (int ni = 0; ni < 3; ++ni) {
      float v0 = acc[mi][ni][0] + bv[ni].x;
      float v1 = acc[mi][ni][1] + bv[ni].y;
      float v2 = acc[mi][ni][2] + bv[ni].z;
      float v3 = acc[mi][ni][3] + bv[ni].w;
      if (half[ni] == 0) {
        sk += v0 + v1 + v2 + v3;
        ssk += v0 * v0 + v1 * v1 + v2 * v2 + v3 * v3;
      } else if (half[ni] == 1) {
        sq += v0 + v1 + v2 + v3;
        ssq += v0 * v0 + v1 * v1 + v2 * v2 + v3 * v3;
      }
      ushort4 o = {f2bf(v0), f2bf(v1), f2bf(v2), f2bf(v3)};
      *(ushort4*)&Cout[(size_t)row * ldc + c00 + ni * 16] = o;
    }
    if (hk) {
      sk += __shfl_xor(sk, 16); ssk += __shfl_xor(ssk, 16);
      sk += __shfl_xor(sk, 32); ssk += __shfl_xor(ssk, 32);
      if (quad == 0) {
        atomicAdd(&stats[(size_t)row * 4 + 0], sk);
        atomicAdd(&stats[(size_t)row * 4 + 1], ssk);
      }
    }
    if (hq) {
      sq += __shfl_xor(sq, 16); ssq += __shfl_xor(ssq, 16);
      sq += __shfl_xor(sq, 32); ssq += __shfl_xor(ssq, 32);
      if (quad == 0) {
        atomicAdd(&stats[(size_t)row * 4 + 2], sq);
        atomicAdd(&stats[(size_t)row * 4 + 3], ssq);
      }
    }
  }
}

// ---------------------------------------------------------------------------
// gemm3: 64x64-tile, BK=128 via stacked-half staging (two BK=64 halves per
// LDS buffer, same swizzle; half 1 at +4096 u16). Halves barrier-drain
// events 32 -> 16 at unchanged occupancy (grid 512 = 2 blocks/CU binds).
// fp32 out + bias + bf16 v-residual epilogue. (r13 win)
// ---------------------------------------------------------------------------
__global__ __launch_bounds__(256) void mfma_gemm64(
    const u16* __restrict__ A, const u16* __restrict__ Bt,
    const float* __restrict__ bias, const u16* __restrict__ extra,
    float* __restrict__ Cout, int K, int lda, int ldb, int ldc, int eld) {
  __shared__ __align__(16) u16 As[2][8192];   // [buf][half 4096 | 64r x 64]
  __shared__ __align__(16) u16 Bs[2][8192];

  const int tid = threadIdx.x;
  const int wv = tid >> 6;
  const int ln = tid & 63;

  const int id = blockIdx.x;
  const int xcd = id & 7;
  const int sub = id >> 3;
  const int tn = sub & 7;
  const int msub = sub >> 3;
  const int row0 = (xcd * 8 + msub) << 6;
  const int col0 = tn << 6;

  const int lrow = ln >> 3;
  const int lchunk = (ln & 7) ^ lrow;
  const u16* ag = A + (size_t)(row0 + 16 * wv + lrow) * lda + lchunk * 8;
  const u16* bg = Bt + (size_t)(col0 + 16 * wv + lrow) * ldb + lchunk * 8;
  const int lbase = 16 * wv * 64;   // within a half

  const int quad = ln >> 4;
  const int l15 = ln & 15;
  const int r7 = l15 & 7;
  const int wm = (wv & 1) << 5;
  const int wn = (wv >> 1) << 5;

  f32x4 acc[2][2];
#pragma unroll
  for (int i = 0; i < 2; ++i)
#pragma unroll
    for (int j = 0; j < 2; ++j) acc[i][j] = (f32x4){0.f, 0.f, 0.f, 0.f};

#define STAGE128(buf, koff)                                         \
  do {                                                              \
    const u16* a0 = ag + (koff);                                    \
    const u16* b0 = bg + (koff);                                    \
    u16* la = &As[buf][lbase];                                      \
    u16* lb = &Bs[buf][lbase];                                      \
    gll16(a0, la);                                                  \
    gll16(a0 + 8 * (size_t)lda, la + 512);                          \
    gll16(b0, lb);                                                  \
    gll16(b0 + 8 * (size_t)ldb, lb + 512);                          \
    gll16(a0 + 64, la + 4096);                                      \
    gll16(a0 + 64 + 8 * (size_t)lda, la + 4096 + 512);              \
    gll16(b0 + 64, lb + 4096);                                      \
    gll16(b0 + 64 + 8 * (size_t)ldb, lb + 4096 + 512);              \
  } while (0)

  const int nk = K >> 7;    // 16 iterations at K=2048
  STAGE128(0, 0);

  for (int ki = 0; ki < nk; ++ki) {
    __syncthreads();
    if (ki + 1 < nk) STAGE128((ki + 1) & 1, (ki + 1) << 7);

    const char* Ab = (const char*)As[ki & 1];
    const char* Bb = (const char*)Bs[ki & 1];
#pragma unroll
    for (int ks = 0; ks < 4; ++ks) {
      const int hoff = (ks >> 1) * 8192;   // byte offset of half
      const int pc = ((quad + 4 * (ks & 1)) ^ r7) << 4;
      bf16x8 af[2], bfv[2];
#pragma unroll
      for (int mi = 0; mi < 2; ++mi)
        af[mi] = *(const bf16x8*)(Ab + hoff + (wm + 16 * mi + l15) * 128 + pc);
#pragma unroll
      for (int ni = 0; ni < 2; ++ni)
        bfv[ni] = *(const bf16x8*)(Bb + hoff + (wn + 16 * ni + l15) * 128 + pc);
#pragma unroll
      for (int mi = 0; mi < 2; ++mi)
#pragma unroll
        for (int ni = 0; ni < 2; ++ni)
          acc[mi][ni] = __builtin_amdgcn_mfma_f32_16x16x32_bf16(
              bfv[ni], af[mi], acc[mi][ni], 0, 0, 0);
    }
  }
#undef STAGE128

  const int c00 = col0 + wn + (quad << 2);
  float4 bv[2];
#pragma unroll
  for (int ni = 0; ni < 2; ++ni) bv[ni] = *(const float4*)&bias[c00 + ni * 16];

#pragma unroll
  for (int mi = 0; mi < 2; ++mi) {
    const int row = row0 + wm + 16 * mi + l15;
#pragma unroll
    for (int ni = 0; ni < 2; ++ni) {
      const int c = c00 + ni * 16;
      uint2 ex = *(const uint2*)&extra[(size_t)row * eld + c];
      float4 o;
      o.x = acc[mi][ni][0] + bv[ni].x + bf2f_lo(ex.x);
      o.y = acc[mi][ni][1] + bv[ni].y + bf2f_hi(ex.x);
      o.z = acc[mi][ni][2] + bv[ni].z + bf2f_lo(ex.y);
      o.w = acc[mi][ni][3] + bv[ni].w + bf2f_hi(ex.y);
      *(float4*)&Cout[(size_t)row * ldc + c] = o;
    }
  }
}

// ---------------------------------------------------------------------------
// Fused converts + stats zero-init (one launch):
// blocks 0..1023 values fp32->bf16; 1024..1791 W_kqv^T; 1792..2815 W_kernel^T;
// 2816..3839 W_proj^T; 3840..3856 zero LN-stats (17408 floats).
// ---------------------------------------------------------------------------
__global__ __launch_bounds__(256) void fused_cvt(
    const float* __restrict__ values, u16* __restrict__ vals_bf,
    const float* __restrict__ Wkqv, u16* __restrict__ wkqv_t,
    const float* __restrict__ Wker, u16* __restrict__ wker_t,
    const float* __restrict__ Wproj, u16* __restrict__ wproj_t,
    float* __restrict__ stats) {
  __shared__ float t[32][33];
  const int id = blockIdx.x;
  if (id >= 3840) {
    const int i = ((id - 3840) * 256 + threadIdx.x) * 4;
    *(float4*)&stats[i] = (float4){0.f, 0.f, 0.f, 0.f};
    return;
  }
  if (id < 1024) {
    const int i = (id * 256 + threadIdx.x) * 8;
    float4 a = *(const float4*)&values[i];
    float4 b = *(const float4*)&values[i + 4];
    union { u16 u[8]; uint4 v; } pk;
    pk.u[0] = f2bf(a.x); pk.u[1] = f2bf(a.y); pk.u[2] = f2bf(a.z); pk.u[3] = f2bf(a.w);
    pk.u[4] = f2bf(b.x); pk.u[5] = f2bf(b.y); pk.u[6] = f2bf(b.z); pk.u[7] = f2bf(b.w);
    *(uint4*)&vals_bf[i] = pk.v;
    return;
  }
  const float* W; u16* Wt; int K, N, nx, lin;
  if (id < 1792)      { lin = id - 1024; W = Wkqv;  Wt = wkqv_t;  K = 512;  N = 1536; nx = 48; }
  else if (id < 2816) { lin = id - 1792; W = Wker;  Wt = wker_t;  K = 512;  N = 2048; nx = 64; }
  else                { lin = id - 2816; W = Wproj; Wt = wproj_t; K = 2048; N = 512;  nx = 16; }
  const int n0 = (lin % nx) << 5;
  const int k0 = (lin / nx) << 5;
  const int r = threadIdx.x >> 3;
  const int c4 = (threadIdx.x & 7) << 2;
  float4 v = *(const float4*)&W[(size_t)(k0 + r) * N + n0 + c4];
  t[r][c4 + 0] = v.x; t[r][c4 + 1] = v.y; t[r][c4 + 2] = v.z; t[r][c4 + 3] = v.w;
  __syncthreads();
  ushort4 o;
  o.x = f2bf(t[c4 + 0][r]); o.y = f2bf(t[c4 + 1][r]);
  o.z = f2bf(t[c4 + 2][r]); o.w = f2bf(t[c4 + 3][r]);
  *(ushort4*)&Wt[(size_t)(n0 + r) * K + k0 + c4] = o;
}

// ---------------------------------------------------------------------------
// MFMA windowed attention with fused LayerNorm (stats from gemm1 atomics).
// ---------------------------------------------------------------------------
__global__ __launch_bounds__(256) void attn_kernel(
    const u16* __restrict__ kqv, const float* __restrict__ stats,
    const float* __restrict__ gamma, const float* __restrict__ beta,
    u16* __restrict__ ctx) {
  __shared__ __align__(16) u16 Ks[192 * 64];
  __shared__ __align__(16) u16 Vt[64 * 192];
  __shared__ __align__(16) u16 Ps[4 * 16 * 192];
  __shared__ float kr[192], km[192];
  __shared__ float qm[64], qr[64];
  __shared__ float g1[64], b1[64];

  const int bid = blockIdx.x;      // (b*H + h)*32 + tile
  const int tile = bid & 31;
  const int h = (bid >> 5) & 7;
  const int b = bid >> 8;
  const int t0 = tile << 6;

  int g0 = t0 - WIN_;
  if (g0 < 0) g0 = 0;
  if (g0 > S_ - SUB_) g0 = S_ - SUB_;

  const int tid = threadIdx.x;
  const int wv = tid >> 6;
  const int ln = tid & 63;
  const size_t rowb = (size_t)(b * S_);

  // ---- stage K via global_load_lds (pure copy, swizzled) ----
  {
    const int krow = ln >> 3;                 // 0..7
    const int kch = (ln & 7) ^ krow;          // source chunk
#pragma unroll
    for (int it = 0; it < 6; ++it) {
      const int kb = it * 32 + wv * 8;        // wave's 8-key group
      gll16(&kqv[(rowb + g0 + kb + krow) * 1536 + h * 64 + kch * 8],
            &Ks[kb * 64]);
    }
  }
  // ---- phase 0: LN stats -> LDS ----
  if (tid < 192) {
    const size_t rr = rowb + g0 + tid;
    const float s = stats[rr * 4 + 0], ss = stats[rr * 4 + 1];
    const float mu = s * (1.f / 512.f);
    const float var = ss * (1.f / 512.f) - mu * mu;
    const float rs = rsqrtf(var + LN_EPS);
    kr[tid] = rs * 0.125f;
    km[tid] = mu * rs * 0.125f;
  } else {
    const int t = tid - 192;
    const size_t rr = rowb + t0 + t;
    const float s = stats[rr * 4 + 2], ss = stats[rr * 4 + 3];
    const float mu = s * (1.f / 512.f);
    const float var = ss * (1.f / 512.f) - mu * mu;
    qm[t] = mu;
    qr[t] = rsqrtf(var + LN_EPS);
  }
  // ---- stage V^T: uint4 loads, conflict-free u16 scatter stores ----
#pragma unroll
  for (int it = 0; it < 6; ++it) {
    const int item = tid + it * 256;        // 192 keys * 8 d-octets
    const int dg8 = item / 192;
    const int key = item - dg8 * 192;
    union { uint4 v; u16 u[8]; } uu;
    uu.v = *(const uint4*)&kqv[(rowb + g0 + key) * 1536 + 1024 + h * 64 + dg8 * 8];
    const int c = key >> 3;
#pragma unroll
    for (int j = 0; j < 8; ++j) {
      const int d = dg8 * 8 + j;
      const int phys = (c & 24) | ((c ^ d) & 7);
      Vt[d * 192 + phys * 8 + (key & 7)] = uu.u[j];
    }
  }
  __syncthreads();  // K landed (vmcnt drained), stats + V visible

  // ---- stage Q: full LN then x gamma; accumulate g1/b1 ----
#pragma unroll
  for (int it = 0; it < 2; ++it) {
    const int item = tid + it * 256;        // 64 q * 8 chunks
    const int qq = item >> 3, c = item & 7;
    const int phys = c ^ (qq & 7);
    uint4 v = *(const uint4*)&kqv[(rowb + t0 + qq) * 1536 + 512 + h * 64 + c * 8];
    const float mu = qm[qq], rs = qr[qq];
    union { float4 f4[2]; float f[8]; } gl, bl;
    gl.f4[0] = *(const float4*)&gamma[h * 64 + c * 8];
    gl.f4[1] = *(const float4*)&gamma[h * 64 + c * 8 + 4];
    bl.f4[0] = *(const float4*)&beta[h * 64 + c * 8];
    bl.f4[1] = *(const float4*)&beta[h * 64 + c * 8 + 4];
    const float x[8] = {bf2f_lo(v.x), bf2f_hi(v.x), bf2f_lo(v.y), bf2f_hi(v.y),
                        bf2f_lo(v.z), bf2f_hi(v.z), bf2f_lo(v.w), bf2f_hi(v.w)};
    float g1p = 0.f, b1p = 0.f;
    union { u16 u[8]; uint4 v; } pk;
#pragma unroll
    for (int j = 0; j < 8; ++j) {
      const float qp = (x[j] - mu) * rs * gl.f[j] + bl.f[j];  // Q' (ref LN'd q)
      const u16 qg = f2bf(qp * gl.f[j]);                      // QG = Q'*gamma
      pk.u[j] = qg;
      g1p += bf2f(qg);
      b1p += qp * bl.f[j];
    }
    g1p += __shfl_xor(g1p, 1); b1p += __shfl_xor(b1p, 1);
    g1p += __shfl_xor(g1p, 2); b1p += __shfl_xor(b1p, 2);
    g1p += __shfl_xor(g1p, 4); b1p += __shfl_xor(b1p, 4);
    if ((tid & 7) == 0) { g1[qq] = g1p; b1[qq] = b1p * 0.125f; }
    *(uint4*)&Ps[qq * 64 + phys * 8] = pk.v;
  }
  __syncthreads();  // Qs (QG) + g1/b1 visible

  const int quad = ln >> 4;
  const int l15 = ln & 15;
  const int l7 = l15 & 7;
  const int qbase = wv << 4;

  // Q A-fragments (2 k-steps)
  bf16x8 qf[2];
#pragma unroll
  for (int ks = 0; ks < 2; ++ks) {
    const int phys = (ks * 4 + quad) ^ l7;
    qf[ks] = *(const bf16x8*)&Ps[(qbase + l15) * 64 + phys * 8];
  }

  // QK: raw = QG @ k^T
  f32x4 sacc[12];
#pragma unroll
  for (int nt = 0; nt < 12; ++nt) sacc[nt] = (f32x4){0.f, 0.f, 0.f, 0.f};
#pragma unroll
  for (int ks = 0; ks < 2; ++ks) {
    const int phys = (ks * 4 + quad) ^ l7;
#pragma unroll
    for (int nt = 0; nt < 12; ++nt) {
      bf16x8 kf = *(const bf16x8*)&Ks[(nt * 16 + l15) * 64 + phys * 8];
      sacc[nt] = __builtin_amdgcn_mfma_f32_16x16x32_bf16(qf[ks], kf, sacc[nt], 0, 0, 0);
    }
  }

  // per-row window offsets + per-row correction scalars
  int off[4];
  float g1m[4], b1s[4];
#pragma unroll
  for (int r = 0; r < 4; ++r) {
    const int qg = t0 + qbase + quad * 4 + r;
    int st = qg - WIN_;
    if (st < 0) st = 0;
    if (st > S_ - SUB_) st = S_ - SUB_;
    off[r] = st - g0;
    g1m[r] = g1[qbase + quad * 4 + r];
    b1s[r] = b1[qbase + quad * 4 + r];
  }

  // LN-fold correction + mask + row max  (kr/km carry the 1/8 scale)
  float rmax[4] = {-1e30f, -1e30f, -1e30f, -1e30f};
#pragma unroll
  for (int nt = 0; nt < 12; ++nt) {
    const int n = nt * 16 + l15;
    const float rsn = kr[n], mn = km[n];
#pragma unroll
    for (int r = 0; r < 4; ++r) {
      const bool valid = (n >= off[r]) && (n < off[r] + SUB_);
      const float sv = fmaf(rsn, sacc[nt][r], fmaf(-mn, g1m[r], b1s[r]));
      const float v = valid ? sv : -1e30f;
      sacc[nt][r] = v;
      rmax[r] = fmaxf(rmax[r], v);
    }
  }
#pragma unroll
  for (int m = 1; m < 16; m <<= 1)
#pragma unroll
    for (int r = 0; r < 4; ++r) rmax[r] = fmaxf(rmax[r], __shfl_xor(rmax[r], m));

  // exp + row sum
  float rsum[4] = {0.f, 0.f, 0.f, 0.f};
#pragma unroll
  for (int nt = 0; nt < 12; ++nt) {
#pragma unroll
    for (int r = 0; r < 4; ++r) {
      const float e = __expf(sacc[nt][r] - rmax[r]);
      sacc[nt][r] = e;
      rsum[r] += e;
    }
  }
#pragma unroll
  for (int m = 1; m < 16; m <<= 1)
#pragma unroll
    for (int r = 0; r < 4; ++r) rsum[r] += __shfl_xor(rsum[r], m);
  float inv[4];
#pragma unroll
  for (int r = 0; r < 4; ++r) inv[r] = 1.f / rsum[r];

  __syncthreads();  // QK reads done; Qs region dead

  // write P (bf16, unnormalized) to wave's Ps region, swizzled
  u16* psw = &Ps[wv * 16 * 192];
#pragma unroll
  for (int nt = 0; nt < 12; ++nt) {
    const int n = nt * 16 + l15;
    const int c = n >> 3;
#pragma unroll
    for (int r = 0; r < 4; ++r) {
      const int m = quad * 4 + r;
      const int phys = (c & 24) | ((c ^ m) & 7);
      psw[m * 192 + phys * 8 + (n & 7)] = f2bf(sacc[nt][r]);
    }
  }
  __syncthreads();  // Ps visible

  // PV: O[16 x 64] = P @ (V^T)^T
  f32x4 oacc[4];
#pragma unroll
  for (int nt = 0; nt < 4; ++nt) oacc[nt] = (f32x4){0.f, 0.f, 0.f, 0.f};
#pragma unroll
  for (int ks = 0; ks < 6; ++ks) {
    const int c = ks * 4 + quad;
    const int phys = (c & 24) | ((c ^ l7) & 7);
    bf16x8 pf = *(const bf16x8*)&psw[l15 * 192 + phys * 8];
#pragma unroll
    for (int nt = 0; nt < 4; ++nt) {
      bf16x8 vf = *(const bf16x8*)&Vt[(nt * 16 + l15) * 192 + phys * 8];
      oacc[nt] = __builtin_amdgcn_mfma_f32_16x16x32_bf16(pf, vf, oacc[nt], 0, 0, 0);
    }
  }

  // epilogue
#pragma unroll
  for (int nt = 0; nt < 4; ++nt) {
#pragma unroll
    for (int r = 0; r < 4; ++r) {
      const int row = t0 + qbase + quad * 4 + r;
      const int col = h * 64 + nt * 16 + l15;
      ctx[(rowb + row) * D_ + col] = f2bf(oacc[nt][r] * inv[r]);
    }
  }
}

// ---------------------------------------------------------------------------
extern "C" void kernel_launch(void* const* d_in, const int* in_sizes, int n_in,
                              void* d_out, int out_size, void* d_ws,
                              size_t ws_size, hipStream_t stream) {
  (void)in_sizes; (void)n_in; (void)out_size; (void)ws_size;
  const float* values   = (const float*)d_in[0];
  const float* W_kqv    = (const float*)d_in[1];
  const float* b_kqv    = (const float*)d_in[2];
  const float* ln_gamma = (const float*)d_in[3];
  const float* ln_beta  = (const float*)d_in[4];
  const float* W_kernel = (const float*)d_in[5];
  const float* b_kernel = (const float*)d_in[6];
  const float* W_proj   = (const float*)d_in[7];
  const float* b_proj   = (const float*)d_in[8];
  float* out = (float*)d_out;

  // workspace carve (16-B aligned)
  u16* kqv     = (u16*)d_ws;                     // M x 1536
  u16* vals_bf = kqv + (size_t)M_ * 1536;        // M x 512
  u16* ctx_bf  = vals_bf + (size_t)M_ * 512;     // M x 512
  u16* x_bf    = ctx_bf + (size_t)M_ * 512;      // M x 2048
  u16* wkqv_t  = x_bf + (size_t)M_ * 2048;       // 1536 x 512
  u16* wker_t  = wkqv_t + (size_t)1536 * 512;    // 2048 x 512
  u16* wproj_t = wker_t + (size_t)2048 * 512;    // 512 x 2048
  float* stats = (float*)(wproj_t + (size_t)512 * 2048);  // 17408 fp32

  // converts + stats zero-init (one launch)
  fused_cvt<<<3857, 256, 0, stream>>>(values, vals_bf, W_kqv, wkqv_t,
                                      W_kernel, wker_t, W_proj, wproj_t,
                                      stats);

  // kqv = values @ W_kqv + b_kqv (bf16 out) + LN stats atomics
  mfma_gemm96<<<512, 256, 0, stream>>>(
      vals_bf, wkqv_t, b_kqv, kqv, stats, 512, 512, 512, 1536);

  // MFMA windowed attention with fused LN -> ctx (bf16)
  attn_kernel<<<B_ * H_ * (S_ / 64), 256, 0, stream>>>(
      kqv, stats, ln_gamma, ln_beta, ctx_bf);

  // x = relu(ctx @ W_kernel + b_kernel)  (bf16 out), 128x128, 512 blocks
  mfma_gemm<1><<<512, 256, 0, stream>>>(
      ctx_bf, wker_t, b_kernel, x_bf, 512, 512, 512, KS_, 16);

  // out = x @ W_proj + b_proj + v  (fp32 out, 64x64 tiles BK=128, 512 blocks)
  mfma_gemm64<<<512, 256, 0, stream>>>(
      x_bf, wproj_t, b_proj, kqv + 1024, out, KS_, KS_, KS_, D_, 1536);
}